// Round 4
// baseline (379.597 us; speedup 1.0000x reference)
//
#include <hip/hip_runtime.h>
#include <hip/hip_bf16.h>

#define BATCH 4096

typedef __attribute__((ext_vector_type(8))) short short8;
typedef __attribute__((ext_vector_type(4))) float f32x4;

#define MFMA_BF16 __builtin_amdgcn_mfma_f32_16x16x32_bf16

__device__ __forceinline__ float frelu(float v) { return v > 0.f ? v : 0.f; }
__device__ __forceinline__ unsigned short f2bf(float f) {
    return __builtin_bit_cast(unsigned short, __float2bfloat16(f));
}
__device__ __forceinline__ short8 cvt8(const float* p) {
    float4 a = *(const float4*)p;
    float4 b = *(const float4*)(p + 4);
    short8 r;
    r[0] = (short)f2bf(a.x); r[1] = (short)f2bf(a.y); r[2] = (short)f2bf(a.z); r[3] = (short)f2bf(a.w);
    r[4] = (short)f2bf(b.x); r[5] = (short)f2bf(b.y); r[6] = (short)f2bf(b.z); r[7] = (short)f2bf(b.w);
    return r;
}

// ---------------- prep: permute+cvt weights to bf16 K-contiguous layouts; init out ----------------
__global__ __launch_bounds__(256) void prep_kernel(const float* __restrict__ w2, const float* __restrict__ w3,
                                                   const float* __restrict__ w4, const float* __restrict__ b5,
                                                   unsigned short* __restrict__ w2p, unsigned short* __restrict__ w3p,
                                                   unsigned short* __restrict__ w4p, float* __restrict__ out) {
    int idx = blockIdx.x * 256 + threadIdx.x;
    if (idx < 18432) {
        int oc = idx / 288, k = idx % 288;
        int khw = k / 32, ic = k % 32;
        w2p[idx] = f2bf(w2[oc * 288 + ic * 9 + khw]);
    } else if (idx < 55296) {
        int j = idx - 18432;
        int oc = j / 576, k = j % 576;
        int khw = k / 64, ic = k % 64;
        w3p[j] = f2bf(w3[oc * 576 + ic * 9 + khw]);
    } else if (idx < 546816) {
        int j = idx - 55296;
        int n = j / 960, k = j % 960;
        int pos = k / 64, oc = k % 64;
        w4p[j] = f2bf(w4[n * 960 + oc * 15 + pos]);
    } else if (idx < 555008) {
        int j = idx - 546816;
        out[j] = b5[j & 1];
    } else if (idx < 555223) {
        out[8192 + (idx - 555008)] = 0.f;
    }
}

// ---------------- conv1 (MFMA, LDS-staged): x[B,3,48,64]*w1[32,192] -> x2 bf16 NHWC [B,165,32] ----------------
// Image staged fp32 in LDS (rows padded 64->68 words); K-loop reads LDS, not HBM.
__global__ __launch_bounds__(256) void conv1_mfma(const float* __restrict__ x,
                                                  const float* __restrict__ w1, const float* __restrict__ b1,
                                                  unsigned short* __restrict__ x2, float* __restrict__ red1) {
    __shared__ float xs[3 * 48 * 68];   // 39,168 B
    __shared__ float red[176];
    const int img = blockIdx.x;
    const int tid = threadIdx.x;
    const int wave = tid >> 6, lane = tid & 63;
    const int col = lane & 15, quad = lane >> 4;

    // stage image: 144 rows x 16 float4, coalesced global, padded LDS rows
    const float4* xg = (const float4*)(x + (size_t)img * 9216);
    for (int i = tid; i < 2304; i += 256) {
        int row = i >> 4, seg = i & 15;
        *(float4*)(xs + row * 68 + seg * 4) = xg[row * 16 + seg];
    }
    if (tid < 176) red[tid] = 0.f;

    // weight fragments: 2 n-tiles x 6 k-chunks, k=(ic,kh,kw)
    short8 Bf[2][6];
    #pragma unroll
    for (int nt = 0; nt < 2; ++nt) {
        const int oc = nt * 16 + col;
        #pragma unroll
        for (int c = 0; c < 6; ++c)
            Bf[nt][c] = cvt8(w1 + oc * 192 + c * 32 + quad * 8);
    }
    const float bias0 = b1[col], bias1 = b1[col + 16];
    __syncthreads();

    #pragma unroll
    for (int ti = 0; ti < 3; ++ti) {
        const int t = wave + ti * 4;          // m-tile, 11 total
        if (t >= 11) break;
        const int posA = t * 16 + col;
        const int pm = posA < 165 ? posA : 164;
        const int oh = pm / 15, ow = pm % 15;
        f32x4 acc0 = {0.f, 0.f, 0.f, 0.f}, acc1 = {0.f, 0.f, 0.f, 0.f};
        #pragma unroll
        for (int c = 0; c < 6; ++c) {
            const int ic = c >> 1;
            const int kh = (c & 1) * 4 + quad;
            const float* ap = xs + ic * 3264 + (oh * 4 + kh) * 68 + ow * 4;
            short8 af = cvt8(ap);
            acc0 = MFMA_BF16(af, Bf[0][c], acc0, 0, 0, 0);
            acc1 = MFMA_BF16(af, Bf[1][c], acc1, 0, 0, 0);
        }
        #pragma unroll
        for (int r = 0; r < 4; ++r) {
            const int pr = t * 16 + quad * 4 + r;
            float v0 = acc0[r] + bias0;
            float v1 = acc1[r] + bias1;
            float s = v0 + v1;
            s += __shfl_xor(s, 1); s += __shfl_xor(s, 2);
            s += __shfl_xor(s, 4); s += __shfl_xor(s, 8);
            if (pr < 165) {
                if (col == 0) atomicAdd(&red[pr], s);
                unsigned short* dst = x2 + ((size_t)img * 165 + pr) * 32;
                dst[col]      = f2bf(frelu(v0));
                dst[col + 16] = f2bf(frelu(v1));
            }
        }
    }
    __syncthreads();
    if (tid < 176) red1[(size_t)tid * 4096 + img] = red[tid];
}

// ---------------- reduce1: ave1[pos] = sum_img red1[pos][img] / 32 ----------------
__global__ __launch_bounds__(256) void reduce1_kernel(const float* __restrict__ red1, float* __restrict__ ave1) {
    const int pos = blockIdx.x;
    float s = 0.f;
    for (int i = threadIdx.x; i < 4096; i += 256) s += red1[(size_t)pos * 4096 + i];
    s += __shfl_down(s, 32); s += __shfl_down(s, 16); s += __shfl_down(s, 8);
    s += __shfl_down(s, 4);  s += __shfl_down(s, 2);  s += __shfl_down(s, 1);
    __shared__ float wsum[4];
    if ((threadIdx.x & 63) == 0) wsum[threadIdx.x >> 6] = s;
    __syncthreads();
    if (threadIdx.x == 0) ave1[pos] = (wsum[0] + wsum[1] + wsum[2] + wsum[3]) * 0.03125f;
}

// ---------------- conv2 (MFMA): x2[B,165,32] * w2p -> x4 bf16 NHWC [B,35,64]; fused ave2 ----------------
// 8960 m-tiles, 8 per block (2/wave) -> 1120 blocks.
__global__ __launch_bounds__(256) void conv2_mfma(const unsigned short* __restrict__ x2,
                                                  const unsigned short* __restrict__ w2p, const float* __restrict__ b2,
                                                  unsigned short* __restrict__ x4, float* __restrict__ ave2) {
    __shared__ unsigned short wl[64 * 296];
    __shared__ float red[35];
    const int tid = threadIdx.x;
    {
        const float4* src = (const float4*)w2p;   // 2304 float4
        for (int i = tid; i < 2304; i += 256) {
            int row = i / 36, off = i % 36;
            *(float4*)((char*)wl + row * 592 + off * 16) = src[i];
        }
    }
    if (tid < 35) red[tid] = 0.f;
    __syncthreads();

    const int wave = tid >> 6, lane = tid & 63;
    const int col = lane & 15, quad = lane >> 4;
    const int tile0 = blockIdx.x * 8 + wave * 2;

    const unsigned short* abase[2];
    #pragma unroll
    for (int mi = 0; mi < 2; ++mi) {
        const int m = (tile0 + mi) * 16 + col;
        const int b = m / 35, pos = m % 35;
        const int oh = pos / 7, ow = pos % 7;
        abase[mi] = x2 + ((size_t)b * 165 + oh * 30 + ow * 2) * 32 + quad * 8;
    }
    f32x4 acc[2][4] = {};
    #pragma unroll
    for (int c = 0; c < 9; ++c) {
        const int kh = c / 3, kw = c % 3;
        short8 Bf[4];
        #pragma unroll
        for (int nt = 0; nt < 4; ++nt)
            Bf[nt] = *(const short8*)((const char*)wl + ((nt * 16 + col) * 296 + c * 32 + quad * 8) * 2);
        #pragma unroll
        for (int mi = 0; mi < 2; ++mi) {
            short8 af = *(const short8*)(abase[mi] + (kh * 15 + kw) * 32);
            #pragma unroll
            for (int nt = 0; nt < 4; ++nt)
                acc[mi][nt] = MFMA_BF16(af, Bf[nt], acc[mi][nt], 0, 0, 0);
        }
    }
    float bv[4];
    #pragma unroll
    for (int nt = 0; nt < 4; ++nt) bv[nt] = b2[nt * 16 + col];
    #pragma unroll
    for (int mi = 0; mi < 2; ++mi) {
        const int mrow0 = (tile0 + mi) * 16;
        #pragma unroll
        for (int r = 0; r < 4; ++r) {
            const int m = mrow0 + quad * 4 + r;
            const int b = m / 35, pos = m % 35;
            unsigned short* dst = x4 + ((size_t)b * 35 + pos) * 64;
            float s = 0.f;
            #pragma unroll
            for (int nt = 0; nt < 4; ++nt) {
                float v = acc[mi][nt][r] + bv[nt];
                s += v;
                dst[nt * 16 + col] = f2bf(frelu(v));
            }
            s += __shfl_xor(s, 1); s += __shfl_xor(s, 2); s += __shfl_xor(s, 4); s += __shfl_xor(s, 8);
            if (col == 0) atomicAdd(&red[pos], s);
        }
    }
    __syncthreads();
    if (tid < 35) atomicAdd(&ave2[tid], red[tid] * 0.015625f);
}

// ---------------- conv3 (MFMA): x4[B,35,64] * w3p -> x6 bf16 [B,960]; fused ave3 ----------------
// 3840 m-tiles, 8 per block -> grid (480, 2); y splits oc halves.
__global__ __launch_bounds__(256) void conv3_mfma(const unsigned short* __restrict__ x4,
                                                  const unsigned short* __restrict__ w3p, const float* __restrict__ b3,
                                                  unsigned short* __restrict__ x6, float* __restrict__ ave3) {
    __shared__ unsigned short wl[32 * 584];
    __shared__ float red[15];
    const int tid = threadIdx.x;
    const int oc0 = blockIdx.y * 32;
    {
        const float4* src = (const float4*)(w3p + (size_t)oc0 * 576);
        for (int i = tid; i < 2304; i += 256) {
            int row = i / 72, off = i % 72;
            *(float4*)((char*)wl + row * 1168 + off * 16) = src[i];
        }
    }
    if (tid < 15) red[tid] = 0.f;
    __syncthreads();

    const int wave = tid >> 6, lane = tid & 63;
    const int col = lane & 15, quad = lane >> 4;
    const int tile0 = blockIdx.x * 8 + wave * 2;

    const unsigned short* abase[2];
    #pragma unroll
    for (int mi = 0; mi < 2; ++mi) {
        const int m = (tile0 + mi) * 16 + col;
        const int b = m / 15, pos = m % 15;
        const int oh = pos / 5, ow = pos % 5;
        abase[mi] = x4 + ((size_t)b * 35 + oh * 7 + ow) * 64 + quad * 8;
    }
    f32x4 acc[2][2] = {};
    #pragma unroll
    for (int c = 0; c < 18; ++c) {
        const int khw = c >> 1, kh = khw / 3, kw = khw % 3;
        const int icoff = (c & 1) * 32;
        short8 Bf[2];
        #pragma unroll
        for (int nt = 0; nt < 2; ++nt)
            Bf[nt] = *(const short8*)((const char*)wl + ((nt * 16 + col) * 584 + c * 32 + quad * 8) * 2);
        #pragma unroll
        for (int mi = 0; mi < 2; ++mi) {
            short8 af = *(const short8*)(abase[mi] + (kh * 7 + kw) * 64 + icoff);
            #pragma unroll
            for (int nt = 0; nt < 2; ++nt)
                acc[mi][nt] = MFMA_BF16(af, Bf[nt], acc[mi][nt], 0, 0, 0);
        }
    }
    float bv[2];
    #pragma unroll
    for (int nt = 0; nt < 2; ++nt) bv[nt] = b3[oc0 + nt * 16 + col];
    #pragma unroll
    for (int mi = 0; mi < 2; ++mi) {
        const int mrow0 = (tile0 + mi) * 16;
        #pragma unroll
        for (int r = 0; r < 4; ++r) {
            const int m = mrow0 + quad * 4 + r;
            const int b = m / 15, pos = m % 15;
            unsigned short* dst = x6 + (size_t)b * 960 + pos * 64 + oc0;
            float s = 0.f;
            #pragma unroll
            for (int nt = 0; nt < 2; ++nt) {
                float v = acc[mi][nt][r] + bv[nt];
                s += v;
                dst[nt * 16 + col] = f2bf(frelu(v));
            }
            s += __shfl_xor(s, 1); s += __shfl_xor(s, 2); s += __shfl_xor(s, 4); s += __shfl_xor(s, 8);
            if (col == 0) atomicAdd(&red[pos], s);
        }
    }
    __syncthreads();
    if (tid < 15) atomicAdd(&ave3[tid], red[tid] * 0.015625f);
}

// ---------------- fc4+fc5 (MFMA, LDS weights): out[b,2] += relu(x6@w4p^T + b4) @ w5^T ----------------
// grid (32,16): 128 m-rows x 32 oc per block; w4p slice staged in LDS (rows padded 960->968).
__global__ __launch_bounds__(256) void fc4_mfma(const unsigned short* __restrict__ x6,
                                                const unsigned short* __restrict__ w4p, const float* __restrict__ b4,
                                                const float* __restrict__ w5, float* __restrict__ out) {
    __shared__ unsigned short wl[32 * 968];   // 61,952 B
    const int tid = threadIdx.x;
    const int wave = tid >> 6, lane = tid & 63;
    const int col = lane & 15, quad = lane >> 4;
    const int m0 = blockIdx.x * 128;
    const int oc0 = blockIdx.y * 32;

    {
        const float4* src = (const float4*)(w4p + (size_t)oc0 * 960);  // 3840 float4
        for (int i = tid; i < 3840; i += 256) {
            int row = i / 120, seg = i % 120;
            *(float4*)((char*)wl + row * 1936 + seg * 16) = src[i];
        }
    }
    __syncthreads();

    const unsigned short* arow0 = x6 + (size_t)(m0 + wave * 32 + col) * 960 + quad * 8;
    const unsigned short* arow1 = arow0 + 16 * 960;
    f32x4 acc[2][2] = {};
    for (int c = 0; c < 30; ++c) {
        short8 Bf[2];
        #pragma unroll
        for (int nt = 0; nt < 2; ++nt)
            Bf[nt] = *(const short8*)((const char*)wl + ((nt * 16 + col) * 968 + c * 32 + quad * 8) * 2);
        short8 a0 = *(const short8*)(arow0 + c * 32);
        short8 a1 = *(const short8*)(arow1 + c * 32);
        #pragma unroll
        for (int nt = 0; nt < 2; ++nt) {
            acc[0][nt] = MFMA_BF16(a0, Bf[nt], acc[0][nt], 0, 0, 0);
            acc[1][nt] = MFMA_BF16(a1, Bf[nt], acc[1][nt], 0, 0, 0);
        }
    }
    float bv[2], w50[2], w51[2];
    #pragma unroll
    for (int nt = 0; nt < 2; ++nt) {
        const int oc = oc0 + nt * 16 + col;
        bv[nt] = b4[oc]; w50[nt] = w5[oc]; w51[nt] = w5[512 + oc];
    }
    #pragma unroll
    for (int mi = 0; mi < 2; ++mi) {
        #pragma unroll
        for (int r = 0; r < 4; ++r) {
            float l0 = 0.f, l1 = 0.f;
            #pragma unroll
            for (int nt = 0; nt < 2; ++nt) {
                float hh = frelu(acc[mi][nt][r] + bv[nt]);
                l0 += hh * w50[nt];
                l1 += hh * w51[nt];
            }
            l0 += __shfl_xor(l0, 1); l0 += __shfl_xor(l0, 2); l0 += __shfl_xor(l0, 4); l0 += __shfl_xor(l0, 8);
            l1 += __shfl_xor(l1, 1); l1 += __shfl_xor(l1, 2); l1 += __shfl_xor(l1, 4); l1 += __shfl_xor(l1, 8);
            if (col == 0) {
                const int gm = m0 + wave * 32 + mi * 16 + quad * 4 + r;
                atomicAdd(&out[gm * 2 + 0], l0);
                atomicAdd(&out[gm * 2 + 1], l1);
            }
        }
    }
}

extern "C" void kernel_launch(void* const* d_in, const int* in_sizes, int n_in,
                              void* d_out, int out_size, void* d_ws, size_t ws_size,
                              hipStream_t stream) {
    const float* x  = (const float*)d_in[0];
    const float* w1 = (const float*)d_in[1];
    const float* b1 = (const float*)d_in[2];
    const float* w2 = (const float*)d_in[3];
    const float* b2 = (const float*)d_in[4];
    const float* w3 = (const float*)d_in[5];
    const float* b3 = (const float*)d_in[6];
    const float* w4 = (const float*)d_in[7];
    const float* b4 = (const float*)d_in[8];
    const float* w5 = (const float*)d_in[9];
    const float* b5 = (const float*)d_in[10];
    float* out = (float*)d_out;

    unsigned short* ws = (unsigned short*)d_ws;
    unsigned short* x2  = ws;                      // 21,626,880 ushort
    unsigned short* x4  = ws + 21626880;           //  9,175,040
    unsigned short* x6  = ws + 30801920;           //  3,932,160
    unsigned short* w2p = ws + 34734080;           //     18,432
    unsigned short* w3p = ws + 34752512;           //     36,864
    unsigned short* w4p = ws + 34789376;           //    491,520
    float* red1 = (float*)((char*)d_ws + 70561792); // 176*4096 floats

    float* ave1 = out + 8192;
    float* ave2 = out + 8192 + 165;
    float* ave3 = out + 8192 + 200;

    prep_kernel<<<2169, 256, 0, stream>>>(w2, w3, w4, b5, w2p, w3p, w4p, out);
    conv1_mfma<<<BATCH, 256, 0, stream>>>(x, w1, b1, x2, red1);
    reduce1_kernel<<<165, 256, 0, stream>>>(red1, ave1);
    conv2_mfma<<<1120, 256, 0, stream>>>(x2, w2p, b2, x4, ave2);
    conv3_mfma<<<dim3(480, 2), 256, 0, stream>>>(x4, w3p, b3, x6, ave3);
    fc4_mfma<<<dim3(32, 16), 256, 0, stream>>>(x6, w4p, b4, w5, out);
}

// Round 5
// 366.026 us; speedup vs baseline: 1.0371x; 1.0371x over previous
//
#include <hip/hip_runtime.h>
#include <hip/hip_bf16.h>

#define BATCH 4096

typedef __attribute__((ext_vector_type(8))) short short8;
typedef __attribute__((ext_vector_type(4))) float f32x4;

#define MFMA_BF16 __builtin_amdgcn_mfma_f32_16x16x32_bf16

__device__ __forceinline__ float frelu(float v) { return v > 0.f ? v : 0.f; }
__device__ __forceinline__ unsigned short f2bf(float f) {
    return __builtin_bit_cast(unsigned short, __float2bfloat16(f));
}
__device__ __forceinline__ unsigned int pack2bf(float a, float b) {
    return (unsigned int)f2bf(a) | ((unsigned int)f2bf(b) << 16);
}
__device__ __forceinline__ short8 cvt8(const float* p) {
    float4 a = *(const float4*)p;
    float4 b = *(const float4*)(p + 4);
    short8 r;
    r[0] = (short)f2bf(a.x); r[1] = (short)f2bf(a.y); r[2] = (short)f2bf(a.z); r[3] = (short)f2bf(a.w);
    r[4] = (short)f2bf(b.x); r[5] = (short)f2bf(b.y); r[6] = (short)f2bf(b.z); r[7] = (short)f2bf(b.w);
    return r;
}
// 16B bf16 fragment from LDS at 8B-aligned address (two b64 reads)
__device__ __forceinline__ short8 lds_frag(const unsigned short* p) {
    uint2 a = *(const uint2*)p;
    uint2 b = *(const uint2*)(p + 4);
    uint4 u = {a.x, a.y, b.x, b.y};
    return __builtin_bit_cast(short8, u);
}

// ---------------- conv1 (+fused weight-prep blocks) ----------------
// blocks [0,4096): x[img] -> x2 bf16 NHWC [B,165,32] + red1 partials.
// Image staged in LDS AS BF16, pitch 68 ushort (136 B = +2 banks/row, conflict-free frag reads).
// blocks [4096,6265): weight permute/cvt + out init (prep).
__global__ __launch_bounds__(256) void conv1_mfma(const float* __restrict__ x,
                                                  const float* __restrict__ w1, const float* __restrict__ b1,
                                                  const float* __restrict__ w2, const float* __restrict__ w3,
                                                  const float* __restrict__ w4, const float* __restrict__ b5,
                                                  unsigned short* __restrict__ x2, float* __restrict__ red1,
                                                  unsigned short* __restrict__ w2p, unsigned short* __restrict__ w3p,
                                                  unsigned short* __restrict__ w4p, float* __restrict__ out) {
    if (blockIdx.x >= 4096) {   // ---- prep path ----
        int idx = (blockIdx.x - 4096) * 256 + threadIdx.x;
        if (idx < 18432) {
            int oc = idx / 288, k = idx % 288;
            int khw = k / 32, ic = k % 32;
            w2p[idx] = f2bf(w2[oc * 288 + ic * 9 + khw]);
        } else if (idx < 55296) {
            int j = idx - 18432;
            int oc = j / 576, k = j % 576;
            int khw = k / 64, ic = k % 64;
            w3p[j] = f2bf(w3[oc * 576 + ic * 9 + khw]);
        } else if (idx < 546816) {
            int j = idx - 55296;
            int n = j / 960, k = j % 960;
            int pos = k / 64, oc = k % 64;
            w4p[j] = f2bf(w4[n * 960 + oc * 15 + pos]);
        } else if (idx < 555008) {
            int j = idx - 546816;
            out[j] = b5[j & 1];
        } else if (idx < 555223) {
            out[8192 + (idx - 555008)] = 0.f;
        }
        return;
    }

    __shared__ unsigned short xs[144 * 68];   // 19,584 B, bf16 image, padded rows
    __shared__ float red[176];
    const int img = blockIdx.x;
    const int tid = threadIdx.x;
    const int wave = tid >> 6, lane = tid & 63;
    const int col = lane & 15, quad = lane >> 4;

    // stage: 2304 coalesced float4 loads (9/thread, independent), cvt to bf16, 8B LDS writes
    const float4* xg = (const float4*)(x + (size_t)img * 9216);
    for (int i = tid; i < 2304; i += 256) {
        int row = i >> 4, seg = i & 15;
        float4 v = xg[i];
        uint2 u = {pack2bf(v.x, v.y), pack2bf(v.z, v.w)};
        *(uint2*)(xs + row * 68 + seg * 4) = u;
    }
    if (tid < 176) red[tid] = 0.f;

    // weight fragments: 2 n-tiles x 6 k-chunks, k=(ic,kh,kw)
    short8 Bf[2][6];
    #pragma unroll
    for (int nt = 0; nt < 2; ++nt) {
        const int oc = nt * 16 + col;
        #pragma unroll
        for (int c = 0; c < 6; ++c)
            Bf[nt][c] = cvt8(w1 + oc * 192 + c * 32 + quad * 8);
    }
    const float bias0 = b1[col], bias1 = b1[col + 16];
    __syncthreads();

    #pragma unroll
    for (int ti = 0; ti < 3; ++ti) {
        const int t = wave + ti * 4;          // m-tile, 11 total
        if (t >= 11) break;
        const int posA = t * 16 + col;
        const int pm = posA < 165 ? posA : 164;
        const int oh = pm / 15, ow = pm % 15;

        // all 6 A-frags loaded up front (independent), then 12 MFMAs
        short8 af[6];
        #pragma unroll
        for (int c = 0; c < 6; ++c) {
            const int ic = c >> 1;
            const int kh = (c & 1) * 4 + quad;
            af[c] = lds_frag(xs + (ic * 48 + oh * 4 + kh) * 68 + ow * 4);
        }
        f32x4 acc0 = {0.f, 0.f, 0.f, 0.f}, acc1 = {0.f, 0.f, 0.f, 0.f};
        #pragma unroll
        for (int c = 0; c < 6; ++c) {
            acc0 = MFMA_BF16(af[c], Bf[0][c], acc0, 0, 0, 0);
            acc1 = MFMA_BF16(af[c], Bf[1][c], acc1, 0, 0, 0);
        }
        #pragma unroll
        for (int r = 0; r < 4; ++r) {
            const int pr = t * 16 + quad * 4 + r;
            float v0 = acc0[r] + bias0;
            float v1 = acc1[r] + bias1;
            float s = v0 + v1;
            s += __shfl_xor(s, 1); s += __shfl_xor(s, 2);
            s += __shfl_xor(s, 4); s += __shfl_xor(s, 8);
            if (pr < 165) {
                if (col == 0) atomicAdd(&red[pr], s);
                unsigned short* dst = x2 + ((size_t)img * 165 + pr) * 32;
                dst[col]      = f2bf(frelu(v0));
                dst[col + 16] = f2bf(frelu(v1));
            }
        }
    }
    __syncthreads();
    if (tid < 176) red1[(size_t)tid * 4096 + img] = red[tid];
}

// ---------------- conv2 (+fused reduce1 blocks) ----------------
// blocks [0,1120): 8 m-tiles each; blocks [1120,1285): ave1[pos] from red1.
__global__ __launch_bounds__(256) void conv2_mfma(const unsigned short* __restrict__ x2,
                                                  const unsigned short* __restrict__ w2p, const float* __restrict__ b2,
                                                  unsigned short* __restrict__ x4, float* __restrict__ ave2,
                                                  const float* __restrict__ red1, float* __restrict__ ave1) {
    __shared__ unsigned short wl[64 * 296];
    __shared__ float red[35];
    const int tid = threadIdx.x;
    if (blockIdx.x >= 1120) {   // ---- reduce1 path ----
        const int pos = blockIdx.x - 1120;
        float s = 0.f;
        for (int i = tid; i < 4096; i += 256) s += red1[(size_t)pos * 4096 + i];
        s += __shfl_down(s, 32); s += __shfl_down(s, 16); s += __shfl_down(s, 8);
        s += __shfl_down(s, 4);  s += __shfl_down(s, 2);  s += __shfl_down(s, 1);
        if ((tid & 63) == 0) red[tid >> 6] = s;
        __syncthreads();
        if (tid == 0) ave1[pos] = (red[0] + red[1] + red[2] + red[3]) * 0.03125f;
        return;
    }
    {
        const float4* src = (const float4*)w2p;   // 2304 float4
        for (int i = tid; i < 2304; i += 256) {
            int row = i / 36, off = i % 36;
            *(float4*)((char*)wl + row * 592 + off * 16) = src[i];
        }
    }
    if (tid < 35) red[tid] = 0.f;
    __syncthreads();

    const int wave = tid >> 6, lane = tid & 63;
    const int col = lane & 15, quad = lane >> 4;
    const int tile0 = blockIdx.x * 8 + wave * 2;

    const unsigned short* abase[2];
    #pragma unroll
    for (int mi = 0; mi < 2; ++mi) {
        const int m = (tile0 + mi) * 16 + col;
        const int b = m / 35, pos = m % 35;
        const int oh = pos / 7, ow = pos % 7;
        abase[mi] = x2 + ((size_t)b * 165 + oh * 30 + ow * 2) * 32 + quad * 8;
    }
    f32x4 acc[2][4] = {};
    #pragma unroll
    for (int c = 0; c < 9; ++c) {
        const int kh = c / 3, kw = c % 3;
        short8 Bf[4];
        #pragma unroll
        for (int nt = 0; nt < 4; ++nt)
            Bf[nt] = *(const short8*)((const char*)wl + ((nt * 16 + col) * 296 + c * 32 + quad * 8) * 2);
        #pragma unroll
        for (int mi = 0; mi < 2; ++mi) {
            short8 af = *(const short8*)(abase[mi] + (kh * 15 + kw) * 32);
            #pragma unroll
            for (int nt = 0; nt < 4; ++nt)
                acc[mi][nt] = MFMA_BF16(af, Bf[nt], acc[mi][nt], 0, 0, 0);
        }
    }
    float bv[4];
    #pragma unroll
    for (int nt = 0; nt < 4; ++nt) bv[nt] = b2[nt * 16 + col];
    #pragma unroll
    for (int mi = 0; mi < 2; ++mi) {
        const int mrow0 = (tile0 + mi) * 16;
        #pragma unroll
        for (int r = 0; r < 4; ++r) {
            const int m = mrow0 + quad * 4 + r;
            const int b = m / 35, pos = m % 35;
            unsigned short* dst = x4 + ((size_t)b * 35 + pos) * 64;
            float s = 0.f;
            #pragma unroll
            for (int nt = 0; nt < 4; ++nt) {
                float v = acc[mi][nt][r] + bv[nt];
                s += v;
                dst[nt * 16 + col] = f2bf(frelu(v));
            }
            s += __shfl_xor(s, 1); s += __shfl_xor(s, 2); s += __shfl_xor(s, 4); s += __shfl_xor(s, 8);
            if (col == 0) atomicAdd(&red[pos], s);
        }
    }
    __syncthreads();
    if (tid < 35) atomicAdd(&ave2[tid], red[tid] * 0.015625f);
}

// ---------------- conv3 (MFMA): x4[B,35,64] * w3p -> x6 bf16 [B,960]; fused ave3 ----------------
__global__ __launch_bounds__(256) void conv3_mfma(const unsigned short* __restrict__ x4,
                                                  const unsigned short* __restrict__ w3p, const float* __restrict__ b3,
                                                  unsigned short* __restrict__ x6, float* __restrict__ ave3) {
    __shared__ unsigned short wl[32 * 584];
    __shared__ float red[15];
    const int tid = threadIdx.x;
    const int oc0 = blockIdx.y * 32;
    {
        const float4* src = (const float4*)(w3p + (size_t)oc0 * 576);
        for (int i = tid; i < 2304; i += 256) {
            int row = i / 72, off = i % 72;
            *(float4*)((char*)wl + row * 1168 + off * 16) = src[i];
        }
    }
    if (tid < 15) red[tid] = 0.f;
    __syncthreads();

    const int wave = tid >> 6, lane = tid & 63;
    const int col = lane & 15, quad = lane >> 4;
    const int tile0 = blockIdx.x * 8 + wave * 2;

    const unsigned short* abase[2];
    #pragma unroll
    for (int mi = 0; mi < 2; ++mi) {
        const int m = (tile0 + mi) * 16 + col;
        const int b = m / 15, pos = m % 15;
        const int oh = pos / 5, ow = pos % 5;
        abase[mi] = x4 + ((size_t)b * 35 + oh * 7 + ow) * 64 + quad * 8;
    }
    f32x4 acc[2][2] = {};
    #pragma unroll
    for (int c = 0; c < 18; ++c) {
        const int khw = c >> 1, kh = khw / 3, kw = khw % 3;
        const int icoff = (c & 1) * 32;
        short8 Bf[2];
        #pragma unroll
        for (int nt = 0; nt < 2; ++nt)
            Bf[nt] = *(const short8*)((const char*)wl + ((nt * 16 + col) * 584 + c * 32 + quad * 8) * 2);
        #pragma unroll
        for (int mi = 0; mi < 2; ++mi) {
            short8 af = *(const short8*)(abase[mi] + (kh * 7 + kw) * 64 + icoff);
            #pragma unroll
            for (int nt = 0; nt < 2; ++nt)
                acc[mi][nt] = MFMA_BF16(af, Bf[nt], acc[mi][nt], 0, 0, 0);
        }
    }
    float bv[2];
    #pragma unroll
    for (int nt = 0; nt < 2; ++nt) bv[nt] = b3[oc0 + nt * 16 + col];
    #pragma unroll
    for (int mi = 0; mi < 2; ++mi) {
        const int mrow0 = (tile0 + mi) * 16;
        #pragma unroll
        for (int r = 0; r < 4; ++r) {
            const int m = mrow0 + quad * 4 + r;
            const int b = m / 15, pos = m % 15;
            unsigned short* dst = x6 + (size_t)b * 960 + pos * 64 + oc0;
            float s = 0.f;
            #pragma unroll
            for (int nt = 0; nt < 2; ++nt) {
                float v = acc[mi][nt][r] + bv[nt];
                s += v;
                dst[nt * 16 + col] = f2bf(frelu(v));
            }
            s += __shfl_xor(s, 1); s += __shfl_xor(s, 2); s += __shfl_xor(s, 4); s += __shfl_xor(s, 8);
            if (col == 0) atomicAdd(&red[pos], s);
        }
    }
    __syncthreads();
    if (tid < 15) atomicAdd(&ave3[tid], red[tid] * 0.015625f);
}

// ---------------- fc4+fc5 (MFMA, LDS weights): out[b,2] += relu(x6@w4p^T + b4) @ w5^T ----------------
__global__ __launch_bounds__(256) void fc4_mfma(const unsigned short* __restrict__ x6,
                                                const unsigned short* __restrict__ w4p, const float* __restrict__ b4,
                                                const float* __restrict__ w5, float* __restrict__ out) {
    __shared__ unsigned short wl[32 * 968];   // 61,952 B
    const int tid = threadIdx.x;
    const int wave = tid >> 6, lane = tid & 63;
    const int col = lane & 15, quad = lane >> 4;
    const int m0 = blockIdx.x * 128;
    const int oc0 = blockIdx.y * 32;

    {
        const float4* src = (const float4*)(w4p + (size_t)oc0 * 960);  // 3840 float4
        for (int i = tid; i < 3840; i += 256) {
            int row = i / 120, seg = i % 120;
            *(float4*)((char*)wl + row * 1936 + seg * 16) = src[i];
        }
    }
    __syncthreads();

    const unsigned short* arow0 = x6 + (size_t)(m0 + wave * 32 + col) * 960 + quad * 8;
    const unsigned short* arow1 = arow0 + 16 * 960;
    f32x4 acc[2][2] = {};
    for (int c = 0; c < 30; ++c) {
        short8 Bf[2];
        #pragma unroll
        for (int nt = 0; nt < 2; ++nt)
            Bf[nt] = *(const short8*)((const char*)wl + ((nt * 16 + col) * 968 + c * 32 + quad * 8) * 2);
        short8 a0 = *(const short8*)(arow0 + c * 32);
        short8 a1 = *(const short8*)(arow1 + c * 32);
        #pragma unroll
        for (int nt = 0; nt < 2; ++nt) {
            acc[0][nt] = MFMA_BF16(a0, Bf[nt], acc[0][nt], 0, 0, 0);
            acc[1][nt] = MFMA_BF16(a1, Bf[nt], acc[1][nt], 0, 0, 0);
        }
    }
    float bv[2], w50[2], w51[2];
    #pragma unroll
    for (int nt = 0; nt < 2; ++nt) {
        const int oc = oc0 + nt * 16 + col;
        bv[nt] = b4[oc]; w50[nt] = w5[oc]; w51[nt] = w5[512 + oc];
    }
    #pragma unroll
    for (int mi = 0; mi < 2; ++mi) {
        #pragma unroll
        for (int r = 0; r < 4; ++r) {
            float l0 = 0.f, l1 = 0.f;
            #pragma unroll
            for (int nt = 0; nt < 2; ++nt) {
                float hh = frelu(acc[mi][nt][r] + bv[nt]);
                l0 += hh * w50[nt];
                l1 += hh * w51[nt];
            }
            l0 += __shfl_xor(l0, 1); l0 += __shfl_xor(l0, 2); l0 += __shfl_xor(l0, 4); l0 += __shfl_xor(l0, 8);
            l1 += __shfl_xor(l1, 1); l1 += __shfl_xor(l1, 2); l1 += __shfl_xor(l1, 4); l1 += __shfl_xor(l1, 8);
            if (col == 0) {
                const int gm = m0 + wave * 32 + mi * 16 + quad * 4 + r;
                atomicAdd(&out[gm * 2 + 0], l0);
                atomicAdd(&out[gm * 2 + 1], l1);
            }
        }
    }
}

extern "C" void kernel_launch(void* const* d_in, const int* in_sizes, int n_in,
                              void* d_out, int out_size, void* d_ws, size_t ws_size,
                              hipStream_t stream) {
    const float* x  = (const float*)d_in[0];
    const float* w1 = (const float*)d_in[1];
    const float* b1 = (const float*)d_in[2];
    const float* w2 = (const float*)d_in[3];
    const float* b2 = (const float*)d_in[4];
    const float* w3 = (const float*)d_in[5];
    const float* b3 = (const float*)d_in[6];
    const float* w4 = (const float*)d_in[7];
    const float* b4 = (const float*)d_in[8];
    const float* w5 = (const float*)d_in[9];
    const float* b5 = (const float*)d_in[10];
    float* out = (float*)d_out;

    unsigned short* ws = (unsigned short*)d_ws;
    unsigned short* x2  = ws;                      // 21,626,880 ushort
    unsigned short* x4  = ws + 21626880;           //  9,175,040
    unsigned short* x6  = ws + 30801920;           //  3,932,160
    unsigned short* w2p = ws + 34734080;           //     18,432
    unsigned short* w3p = ws + 34752512;           //     36,864
    unsigned short* w4p = ws + 34789376;           //    491,520
    float* red1 = (float*)((char*)d_ws + 70561792); // 176*4096 floats

    float* ave1 = out + 8192;
    float* ave2 = out + 8192 + 165;
    float* ave3 = out + 8192 + 200;

    conv1_mfma<<<4096 + 2169, 256, 0, stream>>>(x, w1, b1, w2, w3, w4, b5,
                                                x2, red1, w2p, w3p, w4p, out);
    conv2_mfma<<<1120 + 165, 256, 0, stream>>>(x2, w2p, b2, x4, ave2, red1, ave1);
    conv3_mfma<<<dim3(480, 2), 256, 0, stream>>>(x4, w3p, b3, x6, ave3);
    fc4_mfma<<<dim3(32, 16), 256, 0, stream>>>(x6, w4p, b4, w5, out);
}